// Round 11
// baseline (140.330 us; speedup 1.0000x reference)
//
#include <hip/hip_runtime.h>
#include <hip/hip_bf16.h>

#define DEV __device__ __forceinline__

typedef __attribute__((ext_vector_type(4))) float f32x4;
typedef __bf16 bf16x8 __attribute__((ext_vector_type(8)));

static DEV unsigned short f2bf(float f) {
    union { float f; unsigned u; } x; x.f = f;
    unsigned r = x.u + 0x7fffu + ((x.u >> 16) & 1u);
    return (unsigned short)(r >> 16);
}

static DEV f32x4 zero4() { f32x4 v; v[0] = 0.f; v[1] = 0.f; v[2] = 0.f; v[3] = 0.f; return v; }

#define GL1(p) ((const __attribute__((address_space(1))) void*)(p))
#define LDS3(p) ((__attribute__((address_space(3))) void*)(p))

// ---------------- fused prep: x->bf16, Wa^T->bf16, Wp^T->bf16 ----------------

__global__ __launch_bounds__(256) void k_prep(
    const float* __restrict__ x, unsigned short* __restrict__ xb,
    const float* __restrict__ Wa, unsigned short* __restrict__ WaT,
    const float* __restrict__ Wp, unsigned short* __restrict__ WpT)
{
    int i = blockIdx.x * 256 + threadIdx.x;
    if (i < 3145728) {
        float4 v = reinterpret_cast<const float4*>(x)[i];
        ushort4 o;
        o.x = f2bf(v.x); o.y = f2bf(v.y); o.z = f2bf(v.z); o.w = f2bf(v.w);
        reinterpret_cast<ushort4*>(xb)[i] = o;
    } else if (i < 3145728 + 442368) {
        int j = i - 3145728;
        int n = j / 384, k = j - n * 384;
        WaT[j] = f2bf(Wa[(size_t)k * 1152 + n]);
    } else if (i < 3145728 + 442368 + 147456) {
        int j = i - (3145728 + 442368);
        int n = j / 384, k = j - n * 384;
        WpT[j] = f2bf(Wp[(size_t)k * 384 + n]);
    }
}

// ---------------- GEMM main loops: global_load_lds + XOR-swizzle pair ----------
// Source-granule XOR pre-swizzle + read-side XOR -> conflict-free ds_read_b128.
// SWAP=0: acc holds (4 rows, 1 col); SWAP=1: operands swapped (1 row, 4 cols).

// 512-thread variant: 256(M)x128(N) tile, 8 waves of 64x64.
template <int SWAP>
static DEV void gemm_mainloop512(
    const unsigned short* __restrict__ A,
    const unsigned short* __restrict__ B,
    int m0, int n0, int tid,
    f32x4 (&acc)[4][4],
    unsigned short (&lA)[256][64], unsigned short (&lB)[128][64])
{
    const int K = 384;
    const int w = tid >> 6, lane = tid & 63;
    const int wm = (w >> 1) * 64, wn = (w & 1) * 64;
    const int lr = lane & 15, lg = lane >> 4;
    const int lrow = lane >> 3;                     // dest row within 8-row chunk
    const int lcol = ((lane & 7) ^ lrow) * 8;       // pre-swizzled SOURCE granule

    for (int kb = 0; kb < K; kb += 64) {
        __syncthreads();
#pragma unroll
        for (int c = 0; c < 4; ++c) {
            int rb = w * 32 + c * 8;
            __builtin_amdgcn_global_load_lds(GL1(&A[(size_t)(m0 + rb + lrow) * K + kb + lcol]),
                                             LDS3(&lA[rb][0]), 16, 0, 0);
        }
#pragma unroll
        for (int c = 0; c < 2; ++c) {
            int rb = w * 16 + c * 8;
            __builtin_amdgcn_global_load_lds(GL1(&B[(size_t)(n0 + rb + lrow) * K + kb + lcol]),
                                             LDS3(&lB[rb][0]), 16, 0, 0);
        }
        __syncthreads();

        bf16x8 af[4][2], bfr[4][2];
#pragma unroll
        for (int kc = 0; kc < 2; ++kc) {
#pragma unroll
            for (int t = 0; t < 4; ++t) {
                int ga = ((kc * 4 + lg) ^ (lr & 7)) * 8;   // read-side XOR (same involution)
                af[t][kc]  = *(const bf16x8*)&lA[wm + t * 16 + lr][ga];
                bfr[t][kc] = *(const bf16x8*)&lB[wn + t * 16 + lr][ga];
            }
        }
#pragma unroll
        for (int kc = 0; kc < 2; ++kc)
#pragma unroll
            for (int mt = 0; mt < 4; ++mt)
#pragma unroll
                for (int nt = 0; nt < 4; ++nt)
                    acc[mt][nt] = SWAP
                        ? __builtin_amdgcn_mfma_f32_16x16x32_bf16(bfr[nt][kc], af[mt][kc], acc[mt][nt], 0, 0, 0)
                        : __builtin_amdgcn_mfma_f32_16x16x32_bf16(af[mt][kc], bfr[nt][kc], acc[mt][nt], 0, 0, 0);
    }
}

// 256-thread variant (proj): 128x128 tile, 4 waves.
template <int SWAP>
static DEV void gemm_mainloop(
    const unsigned short* __restrict__ A,
    const unsigned short* __restrict__ B,
    int m0, int n0, int tid,
    f32x4 (&acc)[4][4],
    unsigned short (&lA)[128][64], unsigned short (&lB)[128][64])
{
    const int K = 384;
    const int w = tid >> 6, lane = tid & 63;
    const int wm = (w >> 1) * 64, wn = (w & 1) * 64;
    const int lr = lane & 15, lg = lane >> 4;
    const int lrow = lane >> 3;
    const int lcol = ((lane & 7) ^ lrow) * 8;

    for (int kb = 0; kb < K; kb += 64) {
        __syncthreads();
#pragma unroll
        for (int c = 0; c < 4; ++c) {
            int rb = (w * 4 + c) * 8;
            __builtin_amdgcn_global_load_lds(GL1(&A[(size_t)(m0 + rb + lrow) * K + kb + lcol]),
                                             LDS3(&lA[rb][0]), 16, 0, 0);
            __builtin_amdgcn_global_load_lds(GL1(&B[(size_t)(n0 + rb + lrow) * K + kb + lcol]),
                                             LDS3(&lB[rb][0]), 16, 0, 0);
        }
        __syncthreads();

        bf16x8 af[4][2], bfr[4][2];
#pragma unroll
        for (int kc = 0; kc < 2; ++kc) {
#pragma unroll
            for (int t = 0; t < 4; ++t) {
                int ga = ((kc * 4 + lg) ^ (lr & 7)) * 8;
                af[t][kc]  = *(const bf16x8*)&lA[wm + t * 16 + lr][ga];
                bfr[t][kc] = *(const bf16x8*)&lB[wn + t * 16 + lr][ga];
            }
        }
#pragma unroll
        for (int kc = 0; kc < 2; ++kc)
#pragma unroll
            for (int mt = 0; mt < 4; ++mt)
#pragma unroll
                for (int nt = 0; nt < 4; ++nt)
                    acc[mt][nt] = SWAP
                        ? __builtin_amdgcn_mfma_f32_16x16x32_bf16(bfr[nt][kc], af[mt][kc], acc[mt][nt], 0, 0, 0)
                        : __builtin_amdgcn_mfma_f32_16x16x32_bf16(af[mt][kc], bfr[nt][kc], acc[mt][nt], 0, 0, 0);
    }
}

// ---------------- QKV GEMM: 512t, grid (9 cols, 128 m-tiles) -------------------
// Col-tiles dispatch-adjacent per A-panel -> L2 locality. Fragment-major epilogues.

__global__ __launch_bounds__(512) void k_gemm_qkv(
    const unsigned short* __restrict__ A,
    const unsigned short* __restrict__ B,
    unsigned short* __restrict__ Qb, unsigned short* __restrict__ Kb,
    unsigned short* __restrict__ Vb)
{
    __shared__ unsigned short lA[256][64];
    __shared__ unsigned short lB[128][64];

    const int tid = threadIdx.x;
    const int bx = blockIdx.x;                       // col tile 0..8
    const int m0 = blockIdx.y * 256, n0 = bx * 128;
    const int w = tid >> 6, lane = tid & 63;
    const int wm = (w >> 1) * 64, wn = (w & 1) * 64;
    const int lr = lane & 15, lg = lane >> 4;

    f32x4 acc[4][4];
#pragma unroll
    for (int i = 0; i < 4; i++)
#pragma unroll
        for (int j = 0; j < 4; j++) acc[i][j] = zero4();

    if (bx < 6) {
        gemm_mainloop512<1>(A, B, m0, n0, tid, acc, lA, lB);
        const int which = bx / 3;                    // 0=Q, 1=K
#pragma unroll
        for (int mt = 0; mt < 4; ++mt) {
            int row = m0 + wm + mt * 16 + lr;
            int bb = row >> 10, tloc = row & 1023;
#pragma unroll
            for (int nt = 0; nt < 4; ++nt) {
                int col = n0 + wn + nt * 16 + lg * 4;
                int c = col - which * 384;
                int hh = c >> 6, d0 = c & 63;
                size_t bh = (size_t)bb * 6 + hh;
                int kc = (d0 >> 5) & 1;
                int ln = (tloc & 15) + 16 * ((d0 >> 3) & 3);
                int e0 = d0 & 7;
                union { __bf16 h4[4]; uint2 u; } pk;
                if (which == 0) {
#pragma unroll
                    for (int r = 0; r < 4; ++r)
                        pk.h4[r] = (__bf16)(acc[mt][nt][r] * 0.18033688f); // 1/8 * log2(e)
                    int qt = tloc >> 5, fmt = (tloc >> 4) & 1;
                    *(uint2*)&Qb[((((bh * 32 + qt) * 2 + fmt) * 2 + kc) * 64 + ln) * 8 + e0] = pk.u;
                } else {
#pragma unroll
                    for (int r = 0; r < 4; ++r)
                        pk.h4[r] = (__bf16)acc[mt][nt][r];
                    int ktt = tloc >> 6, fnt = (tloc >> 4) & 3;
                    *(uint2*)&Kb[((((bh * 16 + ktt) * 4 + fnt) * 2 + kc) * 64 + ln) * 8 + e0] = pk.u;
                }
            }
        }
    } else {
        gemm_mainloop512<0>(A, B, m0, n0, tid, acc, lA, lB);
#pragma unroll
        for (int nt = 0; nt < 4; ++nt) {
            int col = n0 + wn + nt * 16 + lr;
            int c = col - 768;
            int hh = c >> 6, d = c & 63;
            int fnt = d >> 4;
#pragma unroll
            for (int mt = 0; mt < 4; ++mt) {
                int row0 = m0 + wm + mt * 16 + lg * 4;
                int bb = row0 >> 10, t0 = row0 & 1023;
                size_t bh = (size_t)bb * 6 + hh;
                int ktt = t0 >> 6, kc = (t0 >> 5) & 1, e0 = t0 & 7;
                int ln = (d & 15) + 16 * ((t0 >> 3) & 3);
                union { __bf16 h4[4]; uint2 u; } pk;
#pragma unroll
                for (int r = 0; r < 4; ++r)
                    pk.h4[r] = (__bf16)acc[mt][nt][r];
                *(uint2*)&Vb[((((bh * 16 + ktt) * 4 + fnt) * 2 + kc) * 64 + ln) * 8 + e0] = pk.u;
            }
        }
    }
}

// ---------------- proj GEMM: 256t, grid (3 cols, 256 m-tiles) ------------------

__global__ __launch_bounds__(256) void k_gemm_proj(
    const unsigned short* __restrict__ A,
    const unsigned short* __restrict__ B,
    const float* __restrict__ bias, float* __restrict__ Out)
{
    __shared__ unsigned short lA[128][64];
    __shared__ unsigned short lB[128][64];

    const int tid = threadIdx.x;
    const int m0 = blockIdx.y * 128, n0 = blockIdx.x * 128;
    const int w = tid >> 6, lane = tid & 63;
    const int wm = (w >> 1) * 64, wn = (w & 1) * 64;
    const int lr = lane & 15, lg = lane >> 4;

    f32x4 acc[4][4];
#pragma unroll
    for (int i = 0; i < 4; i++)
#pragma unroll
        for (int j = 0; j < 4; j++) acc[i][j] = zero4();

    gemm_mainloop<1>(A, B, m0, n0, tid, acc, lA, lB);

#pragma unroll
    for (int mt = 0; mt < 4; ++mt) {
        int row = m0 + wm + mt * 16 + lr;
#pragma unroll
        for (int nt = 0; nt < 4; ++nt) {
            int col = n0 + wn + nt * 16 + lg * 4;
            f32x4 bv = *(const f32x4*)&bias[col];
            f32x4 ov;
#pragma unroll
            for (int r = 0; r < 4; ++r) ov[r] = acc[mt][nt][r] + bv[r];
            *(f32x4*)&Out[(size_t)row * 384 + col] = ov;
        }
    }
}

// ---------------- flash attention, fixed-max (exp2), LDS-staged shared K/V ------
// Block = 1 bh; one PASS = 4 waves on qtiles {4g..4g+3}. Each block runs two
// passes (g, 7-g) -> every block does exactly 18 staging steps (balanced).
// PV uses swapped operands: O col=q(lr) -> per-lane inv, packed stores.

template <int NTM, bool MASK>
static DEV void attn_tile(
    const unsigned short* lKt, const unsigned short* lVt, unsigned short* lPw,
    const bf16x8 (&qf)[2][2], f32x4 (&o)[2][4], float (&ls)[2],
    int kt, int qw, int lane)
{
    constexpr int KCM = NTM / 2;
    const int lr = lane & 15, lg = lane >> 4;

    bf16x8 kf[NTM][2];
#pragma unroll
    for (int nt = 0; nt < NTM; ++nt)
#pragma unroll
        for (int kc = 0; kc < 2; ++kc)
            kf[nt][kc] = *(const bf16x8*)&lKt[(nt * 2 + kc) * 512 + lane * 8];

    bf16x8 vf[4][KCM];
#pragma unroll
    for (int nt = 0; nt < 4; ++nt)
#pragma unroll
        for (int kc = 0; kc < KCM; ++kc)
            vf[nt][kc] = *(const bf16x8*)&lVt[(nt * 2 + kc) * 512 + lane * 8];

    // S^T = K * Q^T : lane holds q = mt*16+lr, k = nt*16+lg*4+r
    f32x4 st[2][NTM];
#pragma unroll
    for (int mt = 0; mt < 2; ++mt)
#pragma unroll
        for (int nt = 0; nt < NTM; ++nt) st[mt][nt] = zero4();

    __builtin_amdgcn_s_setprio(1);
#pragma unroll
    for (int kc = 0; kc < 2; ++kc)
#pragma unroll
        for (int mt = 0; mt < 2; ++mt)
#pragma unroll
            for (int nt = 0; nt < NTM; ++nt)
                st[mt][nt] = __builtin_amdgcn_mfma_f32_16x16x32_bf16(kf[nt][kc], qf[mt][kc], st[mt][nt], 0, 0, 0);
    __builtin_amdgcn_s_setprio(0);

    // exp2 (fixed max), tree rowsum partials, pack bf16, write P in FRAGMENT layout
#pragma unroll
    for (int mt = 0; mt < 2; ++mt) {
#pragma unroll
        for (int nt = 0; nt < NTM; ++nt) {
            union { __bf16 hh[4]; uint2 u; } pk;
            float e[4];
#pragma unroll
            for (int r = 0; r < 4; ++r) {
                float ev = __builtin_amdgcn_exp2f(st[mt][nt][r]);
                if (MASK) {
                    int kg = kt * 64 + nt * 16 + lg * 4 + r;
                    int qg = qw + mt * 16 + lr;
                    if (kg > qg) ev = 0.f;
                }
                e[r] = ev;
                pk.hh[r] = (__bf16)ev;
            }
            ls[mt] += (e[0] + e[1]) + (e[2] + e[3]);
            // P[q][k] -> A-fragment slot: kc=nt>>1, lane'=lr+16*((nt&1)*2+(lg>>1)), e'=(lg&1)*4+r
            int ln2 = lr + 16 * ((nt & 1) * 2 + (lg >> 1));
            *(uint2*)&lPw[(mt * 2 + (nt >> 1)) * 512 + ln2 * 8 + (lg & 1) * 4] = pk.u;
        }
    }

    bf16x8 pf[2][KCM];
#pragma unroll
    for (int mt = 0; mt < 2; ++mt)
#pragma unroll
        for (int kc = 0; kc < KCM; ++kc)
            pf[mt][kc] = *(const bf16x8*)&lPw[(mt * 2 + kc) * 512 + lane * 8];

    // PV swapped: o[mt][nt] = O[q = mt*16+lr][d = nt*16+lg*4+r]
    __builtin_amdgcn_s_setprio(1);
#pragma unroll
    for (int mt = 0; mt < 2; ++mt)
#pragma unroll
        for (int nt = 0; nt < 4; ++nt)
#pragma unroll
            for (int kc = 0; kc < KCM; ++kc)
                o[mt][nt] = __builtin_amdgcn_mfma_f32_16x16x32_bf16(vf[nt][kc], pf[mt][kc], o[mt][nt], 0, 0, 0);
    __builtin_amdgcn_s_setprio(0);
}

static DEV void attn_pass(
    int gg, int w, int lane, int b, int h, int bh,
    const unsigned short* __restrict__ Qf,
    const unsigned short* __restrict__ Kbh,
    const unsigned short* __restrict__ Vbh,
    unsigned short* __restrict__ Y,
    unsigned short (&lK)[2][4096], unsigned short (&lV)[2][4096],
    unsigned short* lPw)
{
    const int lr = lane & 15, lg = lane >> 4;
    const int qt = 4 * gg + w;
    const int qw = qt * 32;
    const int nkt = qt / 2 + 1;
    const int nsteps = 2 * gg + 2;

    bf16x8 qf[2][2];
#pragma unroll
    for (int mt = 0; mt < 2; ++mt)
#pragma unroll
        for (int kc = 0; kc < 2; ++kc)
            qf[mt][kc] = *(const bf16x8*)&Qf[((((size_t)bh * 32 + qt) * 2 + mt) * 2 + kc) * 512 + lane * 8];

    f32x4 o[2][4];
    float ls[2] = {0.f, 0.f};
#pragma unroll
    for (int mt = 0; mt < 2; ++mt)
#pragma unroll
        for (int nt = 0; nt < 4; ++nt) o[mt][nt] = zero4();

    // make sure all waves finished reading LDS from the previous pass
    __syncthreads();

    // prologue stage: tile 0 -> buf 0 (each wave stages its 2KB of K and V)
#pragma unroll
    for (int i = 0; i < 2; ++i) {
        __builtin_amdgcn_global_load_lds(GL1(Kbh + (size_t)w * 1024 + i * 512 + lane * 8),
                                         LDS3(&lK[0][w * 1024 + i * 512]), 16, 0, 0);
        __builtin_amdgcn_global_load_lds(GL1(Vbh + (size_t)w * 1024 + i * 512 + lane * 8),
                                         LDS3(&lV[0][w * 1024 + i * 512]), 16, 0, 0);
    }

    for (int kt = 0; kt < nsteps; ++kt) {
        __syncthreads();   // drains vmcnt -> buf[kt&1] ready; lgkm -> prev reads done
        if (kt + 1 < nsteps) {
            int nb = (kt + 1) & 1;
#pragma unroll
            for (int i = 0; i < 2; ++i) {
                __builtin_amdgcn_global_load_lds(GL1(Kbh + (size_t)(kt + 1) * 4096 + w * 1024 + i * 512 + lane * 8),
                                                 LDS3(&lK[nb][w * 1024 + i * 512]), 16, 0, 0);
                __builtin_amdgcn_global_load_lds(GL1(Vbh + (size_t)(kt + 1) * 4096 + w * 1024 + i * 512 + lane * 8),
                                                 LDS3(&lV[nb][w * 1024 + i * 512]), 16, 0, 0);
            }
        }
        if (kt < nkt) {
            const unsigned short* lKt = lK[kt & 1];
            const unsigned short* lVt = lV[kt & 1];
            if (kt == nkt - 1) {
                if (qt & 1) attn_tile<4, true>(lKt, lVt, lPw, qf, o, ls, kt, qw, lane);
                else        attn_tile<2, true>(lKt, lVt, lPw, qf, o, ls, kt, qw, lane);
            } else {
                attn_tile<4, false>(lKt, lVt, lPw, qf, o, ls, kt, qw, lane);
            }
        }
    }

    // deferred row-sum reduction (per-lane full sum for q=lr) + packed output
    float inv[2];
#pragma unroll
    for (int mt = 0; mt < 2; ++mt) {
        float s = ls[mt];
        s += __shfl_xor(s, 16);
        s += __shfl_xor(s, 32);
        inv[mt] = 1.0f / s;
    }
#pragma unroll
    for (int mt = 0; mt < 2; ++mt) {
#pragma unroll
        for (int nt = 0; nt < 4; ++nt) {
            union { __bf16 h4[4]; uint2 u; } pk;
#pragma unroll
            for (int r = 0; r < 4; ++r) pk.h4[r] = (__bf16)(o[mt][nt][r] * inv[mt]);
            *(uint2*)&Y[((size_t)b * 1024 + qw + mt * 16 + lr) * 384 + h * 64 + nt * 16 + lg * 4] = pk.u;
        }
    }
}

__global__ __launch_bounds__(256, 3) void k_attn(
    const unsigned short* __restrict__ Qf,
    const unsigned short* __restrict__ Kf,
    const unsigned short* __restrict__ Vf,
    unsigned short* __restrict__ Y)
{
    __shared__ unsigned short lK[2][4096];
    __shared__ unsigned short lV[2][4096];
    __shared__ unsigned short lPf[4][2048];

    const int tid = threadIdx.x;
    const int w = tid >> 6, lane = tid & 63;
    const int bh = blockIdx.x;
    const int g = blockIdx.y;                // 0..3; block runs passes g and 7-g
    const int b = bh / 6, h = bh - b * 6;

    const unsigned short* Kbh = Kf + (size_t)bh * 65536;
    const unsigned short* Vbh = Vf + (size_t)bh * 65536;

    attn_pass(g,     w, lane, b, h, bh, Qf, Kbh, Vbh, Y, lK, lV, lPf[w]);
    attn_pass(7 - g, w, lane, b, h, bh, Qf, Kbh, Vbh, Y, lK, lV, lPf[w]);
}

// ---------------- launcher ----------------

extern "C" void kernel_launch(void* const* d_in, const int* in_sizes, int n_in,
                              void* d_out, int out_size, void* d_ws, size_t ws_size,
                              hipStream_t stream)
{
    const float* x  = (const float*)d_in[0];
    const float* Wa = (const float*)d_in[1];
    const float* Wp = (const float*)d_in[2];
    const float* bp = (const float*)d_in[3];
    float* out = (float*)d_out;

    char* ws = (char*)d_ws;
    unsigned short* xb  = (unsigned short*)(ws);              // 25165824 B; reused as Y after attn
    unsigned short* WaT = (unsigned short*)(ws + 25165824);   // 884736 B
    unsigned short* WpT = (unsigned short*)(ws + 26050560);   // 294912 B
    unsigned short* Qb  = (unsigned short*)(ws + 26345472);   // 25165824 B (fragment-major)
    unsigned short* Kb  = (unsigned short*)(ws + 51511296);   // 25165824 B (fragment-major)
    unsigned short* Vtb = (unsigned short*)(ws + 76677120);   // 25165824 B (fragment-major)

    k_prep<<<14592, 256, 0, stream>>>(x, xb, Wa, WaT, Wp, WpT);
    k_gemm_qkv<<<dim3(9, 128), 512, 0, stream>>>(xb, WaT, Qb, Kb, Vtb);
    k_attn<<<dim3(192, 4), 256, 0, stream>>>(Qb, Kb, Vtb, xb);
    k_gemm_proj<<<dim3(3, 256), 256, 0, stream>>>(xb, WpT, bp, out);
}

// Round 12
// 122.589 us; speedup vs baseline: 1.1447x; 1.1447x over previous
//
#include <hip/hip_runtime.h>
#include <hip/hip_bf16.h>

#define DEV __device__ __forceinline__

typedef __attribute__((ext_vector_type(4))) float f32x4;
typedef __bf16 bf16x8 __attribute__((ext_vector_type(8)));

static DEV unsigned short f2bf(float f) {
    union { float f; unsigned u; } x; x.f = f;
    unsigned r = x.u + 0x7fffu + ((x.u >> 16) & 1u);
    return (unsigned short)(r >> 16);
}

static DEV f32x4 zero4() { f32x4 v; v[0] = 0.f; v[1] = 0.f; v[2] = 0.f; v[3] = 0.f; return v; }

#define GL1(p) ((const __attribute__((address_space(1))) void*)(p))
#define LDS3(p) ((__attribute__((address_space(3))) void*)(p))

// ---------------- fused prep: x->bf16, Wa^T->bf16, Wp^T->bf16 ----------------

__global__ __launch_bounds__(256) void k_prep(
    const float* __restrict__ x, unsigned short* __restrict__ xb,
    const float* __restrict__ Wa, unsigned short* __restrict__ WaT,
    const float* __restrict__ Wp, unsigned short* __restrict__ WpT)
{
    int i = blockIdx.x * 256 + threadIdx.x;
    if (i < 3145728) {
        float4 v = reinterpret_cast<const float4*>(x)[i];
        ushort4 o;
        o.x = f2bf(v.x); o.y = f2bf(v.y); o.z = f2bf(v.z); o.w = f2bf(v.w);
        reinterpret_cast<ushort4*>(xb)[i] = o;
    } else if (i < 3145728 + 442368) {
        int j = i - 3145728;
        int n = j / 384, k = j - n * 384;
        WaT[j] = f2bf(Wa[(size_t)k * 1152 + n]);
    } else if (i < 3145728 + 442368 + 147456) {
        int j = i - (3145728 + 442368);
        int n = j / 384, k = j - n * 384;
        WpT[j] = f2bf(Wp[(size_t)k * 384 + n]);
    }
}

// ---------------- GEMM main loop (r8/r10 single-buffer, m97-optimum) -----------
// global_load_lds width-16 staging; source-granule XOR-swizzle paired with
// read-side XOR -> conflict-free ds_read_b128.
// SWAP=0: acc holds (4 rows, 1 col); SWAP=1: operands swapped (1 row, 4 cols).

template <int SWAP>
static DEV void gemm_mainloop(
    const unsigned short* __restrict__ A,
    const unsigned short* __restrict__ B,
    int m0, int n0, int tid,
    f32x4 (&acc)[4][4],
    unsigned short (&lA)[128][64], unsigned short (&lB)[128][64])
{
    const int K = 384;
    const int w = tid >> 6, lane = tid & 63;
    const int wm = (w >> 1) * 64, wn = (w & 1) * 64;
    const int lr = lane & 15, lg = lane >> 4;
    const int lrow = lane >> 3;                     // dest row within 8-row chunk
    const int lcol = ((lane & 7) ^ lrow) * 8;       // pre-swizzled SOURCE granule

    for (int kb = 0; kb < K; kb += 64) {
        __syncthreads();
#pragma unroll
        for (int c = 0; c < 4; ++c) {
            int rb = (w * 4 + c) * 8;
            __builtin_amdgcn_global_load_lds(GL1(&A[(size_t)(m0 + rb + lrow) * K + kb + lcol]),
                                             LDS3(&lA[rb][0]), 16, 0, 0);
            __builtin_amdgcn_global_load_lds(GL1(&B[(size_t)(n0 + rb + lrow) * K + kb + lcol]),
                                             LDS3(&lB[rb][0]), 16, 0, 0);
        }
        __syncthreads();

        bf16x8 af[4][2], bfr[4][2];
#pragma unroll
        for (int kc = 0; kc < 2; ++kc) {
#pragma unroll
            for (int t = 0; t < 4; ++t) {
                int ga = ((kc * 4 + lg) ^ (lr & 7)) * 8;   // read-side XOR (same involution)
                af[t][kc]  = *(const bf16x8*)&lA[wm + t * 16 + lr][ga];
                bfr[t][kc] = *(const bf16x8*)&lB[wn + t * 16 + lr][ga];
            }
        }
#pragma unroll
        for (int kc = 0; kc < 2; ++kc)
#pragma unroll
            for (int mt = 0; mt < 4; ++mt)
#pragma unroll
                for (int nt = 0; nt < 4; ++nt)
                    acc[mt][nt] = SWAP
                        ? __builtin_amdgcn_mfma_f32_16x16x32_bf16(bfr[nt][kc], af[mt][kc], acc[mt][nt], 0, 0, 0)
                        : __builtin_amdgcn_mfma_f32_16x16x32_bf16(af[mt][kc], bfr[nt][kc], acc[mt][nt], 0, 0, 0);
    }
}

// ---------------- QKV GEMM: XCD-aware linear grid (2304 = 8 xcd * 32 m * 9 col) -
// Same-A-panel blocks are consecutive slots on ONE XCD -> panel stays L2-hot.

__global__ __launch_bounds__(256) void k_gemm_qkv(
    const unsigned short* __restrict__ A,
    const unsigned short* __restrict__ B,
    unsigned short* __restrict__ Qb, unsigned short* __restrict__ Kb,
    unsigned short* __restrict__ Vb)
{
    __shared__ unsigned short lA[128][64];
    __shared__ unsigned short lB[128][64];

    const int bid = blockIdx.x;
    const int xcd = bid & 7, s = bid >> 3;
    const int mi = xcd * 32 + s / 9;          // 0..255 (m-tile)
    const int cj = s % 9;                     // 0..8  (col-tile)
    const int m0 = mi * 128, n0 = cj * 128;

    const int tid = threadIdx.x;
    const int w = tid >> 6, lane = tid & 63;
    const int wm = (w >> 1) * 64, wn = (w & 1) * 64;
    const int lr = lane & 15, lg = lane >> 4;

    f32x4 acc[4][4];
#pragma unroll
    for (int i = 0; i < 4; i++)
#pragma unroll
        for (int j = 0; j < 4; j++) acc[i][j] = zero4();

    if (cj < 6) {
        gemm_mainloop<1>(A, B, m0, n0, tid, acc, lA, lB);
        const int which = cj / 3;             // 0=Q, 1=K
#pragma unroll
        for (int mt = 0; mt < 4; ++mt) {
            int row = m0 + wm + mt * 16 + lr;
            int bb = row >> 10, tloc = row & 1023;
#pragma unroll
            for (int nt = 0; nt < 4; ++nt) {
                int col = n0 + wn + nt * 16 + lg * 4;
                int c = col - which * 384;
                int hh = c >> 6, d0 = c & 63;
                size_t bh = (size_t)bb * 6 + hh;
                int kc = (d0 >> 5) & 1;
                int ln = (tloc & 15) + 16 * ((d0 >> 3) & 3);
                int e0 = d0 & 7;
                union { __bf16 h4[4]; uint2 u; } pk;
                if (which == 0) {
#pragma unroll
                    for (int r = 0; r < 4; ++r)
                        pk.h4[r] = (__bf16)(acc[mt][nt][r] * 0.18033688f); // 1/8 * log2(e)
                    int qt = tloc >> 5, fmt = (tloc >> 4) & 1;
                    *(uint2*)&Qb[((((bh * 32 + qt) * 2 + fmt) * 2 + kc) * 64 + ln) * 8 + e0] = pk.u;
                } else {
#pragma unroll
                    for (int r = 0; r < 4; ++r)
                        pk.h4[r] = (__bf16)acc[mt][nt][r];
                    int ktt = tloc >> 6, fnt = (tloc >> 4) & 3;
                    *(uint2*)&Kb[((((bh * 16 + ktt) * 4 + fnt) * 2 + kc) * 64 + ln) * 8 + e0] = pk.u;
                }
            }
        }
    } else {
        gemm_mainloop<0>(A, B, m0, n0, tid, acc, lA, lB);
#pragma unroll
        for (int nt = 0; nt < 4; ++nt) {
            int col = n0 + wn + nt * 16 + lr;
            int c = col - 768;
            int hh = c >> 6, d = c & 63;
            int fnt = d >> 4;
#pragma unroll
            for (int mt = 0; mt < 4; ++mt) {
                int row0 = m0 + wm + mt * 16 + lg * 4;
                int bb = row0 >> 10, t0 = row0 & 1023;
                size_t bh = (size_t)bb * 6 + hh;
                int ktt = t0 >> 6, kc = (t0 >> 5) & 1, e0 = t0 & 7;
                int ln = (d & 15) + 16 * ((t0 >> 3) & 3);
                union { __bf16 h4[4]; uint2 u; } pk;
#pragma unroll
                for (int r = 0; r < 4; ++r)
                    pk.h4[r] = (__bf16)acc[mt][nt][r];
                *(uint2*)&Vb[((((bh * 16 + ktt) * 4 + fnt) * 2 + kc) * 64 + ln) * 8 + e0] = pk.u;
            }
        }
    }
}

// ---------------- proj GEMM: XCD-aware linear grid (768 = 8 * 32 * 3) ----------

__global__ __launch_bounds__(256) void k_gemm_proj(
    const unsigned short* __restrict__ A,
    const unsigned short* __restrict__ B,
    const float* __restrict__ bias, float* __restrict__ Out)
{
    __shared__ unsigned short lA[128][64];
    __shared__ unsigned short lB[128][64];

    const int bid = blockIdx.x;
    const int xcd = bid & 7, s = bid >> 3;
    const int mi = xcd * 32 + s / 3;
    const int cj = s % 3;
    const int m0 = mi * 128, n0 = cj * 128;

    const int tid = threadIdx.x;
    const int w = tid >> 6, lane = tid & 63;
    const int wm = (w >> 1) * 64, wn = (w & 1) * 64;
    const int lr = lane & 15, lg = lane >> 4;

    f32x4 acc[4][4];
#pragma unroll
    for (int i = 0; i < 4; i++)
#pragma unroll
        for (int j = 0; j < 4; j++) acc[i][j] = zero4();

    gemm_mainloop<1>(A, B, m0, n0, tid, acc, lA, lB);

#pragma unroll
    for (int mt = 0; mt < 4; ++mt) {
        int row = m0 + wm + mt * 16 + lr;
#pragma unroll
        for (int nt = 0; nt < 4; ++nt) {
            int col = n0 + wn + nt * 16 + lg * 4;
            f32x4 bv = *(const f32x4*)&bias[col];
            f32x4 ov;
#pragma unroll
            for (int r = 0; r < 4; ++r) ov[r] = acc[mt][nt][r] + bv[r];
            *(f32x4*)&Out[(size_t)row * 384 + col] = ov;
        }
    }
}

// ---------------- flash attention, fixed-max (exp2), LDS-staged shared K/V ------
// Block = 1 bh; one PASS = 4 waves on qtiles {4g..4g+3}. Each block runs two
// passes (g, 7-g) -> every block does exactly 18 staging steps (balanced).
// PV uses swapped operands: O col=q(lr) -> per-lane inv, packed stores.

template <int NTM, bool MASK>
static DEV void attn_tile(
    const unsigned short* lKt, const unsigned short* lVt, unsigned short* lPw,
    const bf16x8 (&qf)[2][2], f32x4 (&o)[2][4], float (&ls)[2],
    int kt, int qw, int lane)
{
    constexpr int KCM = NTM / 2;
    const int lr = lane & 15, lg = lane >> 4;

    bf16x8 kf[NTM][2];
#pragma unroll
    for (int nt = 0; nt < NTM; ++nt)
#pragma unroll
        for (int kc = 0; kc < 2; ++kc)
            kf[nt][kc] = *(const bf16x8*)&lKt[(nt * 2 + kc) * 512 + lane * 8];

    bf16x8 vf[4][KCM];
#pragma unroll
    for (int nt = 0; nt < 4; ++nt)
#pragma unroll
        for (int kc = 0; kc < KCM; ++kc)
            vf[nt][kc] = *(const bf16x8*)&lVt[(nt * 2 + kc) * 512 + lane * 8];

    // S^T = K * Q^T : lane holds q = mt*16+lr, k = nt*16+lg*4+r
    f32x4 st[2][NTM];
#pragma unroll
    for (int mt = 0; mt < 2; ++mt)
#pragma unroll
        for (int nt = 0; nt < NTM; ++nt) st[mt][nt] = zero4();

    __builtin_amdgcn_s_setprio(1);
#pragma unroll
    for (int kc = 0; kc < 2; ++kc)
#pragma unroll
        for (int mt = 0; mt < 2; ++mt)
#pragma unroll
            for (int nt = 0; nt < NTM; ++nt)
                st[mt][nt] = __builtin_amdgcn_mfma_f32_16x16x32_bf16(kf[nt][kc], qf[mt][kc], st[mt][nt], 0, 0, 0);
    __builtin_amdgcn_s_setprio(0);

    // exp2 (fixed max), tree rowsum partials, pack bf16, write P in FRAGMENT layout
#pragma unroll
    for (int mt = 0; mt < 2; ++mt) {
#pragma unroll
        for (int nt = 0; nt < NTM; ++nt) {
            union { __bf16 hh[4]; uint2 u; } pk;
            float e[4];
#pragma unroll
            for (int r = 0; r < 4; ++r) {
                float ev = __builtin_amdgcn_exp2f(st[mt][nt][r]);
                if (MASK) {
                    int kg = kt * 64 + nt * 16 + lg * 4 + r;
                    int qg = qw + mt * 16 + lr;
                    if (kg > qg) ev = 0.f;
                }
                e[r] = ev;
                pk.hh[r] = (__bf16)ev;
            }
            ls[mt] += (e[0] + e[1]) + (e[2] + e[3]);
            // P[q][k] -> A-fragment slot: kc=nt>>1, lane'=lr+16*((nt&1)*2+(lg>>1)), e'=(lg&1)*4+r
            int ln2 = lr + 16 * ((nt & 1) * 2 + (lg >> 1));
            *(uint2*)&lPw[(mt * 2 + (nt >> 1)) * 512 + ln2 * 8 + (lg & 1) * 4] = pk.u;
        }
    }

    bf16x8 pf[2][KCM];
#pragma unroll
    for (int mt = 0; mt < 2; ++mt)
#pragma unroll
        for (int kc = 0; kc < KCM; ++kc)
            pf[mt][kc] = *(const bf16x8*)&lPw[(mt * 2 + kc) * 512 + lane * 8];

    // PV swapped: o[mt][nt] = O[q = mt*16+lr][d = nt*16+lg*4+r]
    __builtin_amdgcn_s_setprio(1);
#pragma unroll
    for (int mt = 0; mt < 2; ++mt)
#pragma unroll
        for (int nt = 0; nt < 4; ++nt)
#pragma unroll
            for (int kc = 0; kc < KCM; ++kc)
                o[mt][nt] = __builtin_amdgcn_mfma_f32_16x16x32_bf16(vf[nt][kc], pf[mt][kc], o[mt][nt], 0, 0, 0);
    __builtin_amdgcn_s_setprio(0);
}

static DEV void attn_pass(
    int gg, int w, int lane, int b, int h, int bh,
    const unsigned short* __restrict__ Qf,
    const unsigned short* __restrict__ Kbh,
    const unsigned short* __restrict__ Vbh,
    unsigned short* __restrict__ Y,
    unsigned short (&lK)[2][4096], unsigned short (&lV)[2][4096],
    unsigned short* lPw)
{
    const int lr = lane & 15, lg = lane >> 4;
    const int qt = 4 * gg + w;
    const int qw = qt * 32;
    const int nkt = qt / 2 + 1;
    const int nsteps = 2 * gg + 2;

    bf16x8 qf[2][2];
#pragma unroll
    for (int mt = 0; mt < 2; ++mt)
#pragma unroll
        for (int kc = 0; kc < 2; ++kc)
            qf[mt][kc] = *(const bf16x8*)&Qf[((((size_t)bh * 32 + qt) * 2 + mt) * 2 + kc) * 512 + lane * 8];

    f32x4 o[2][4];
    float ls[2] = {0.f, 0.f};
#pragma unroll
    for (int mt = 0; mt < 2; ++mt)
#pragma unroll
        for (int nt = 0; nt < 4; ++nt) o[mt][nt] = zero4();

    // make sure all waves finished reading LDS from the previous pass
    __syncthreads();

    // prologue stage: tile 0 -> buf 0 (each wave stages its 2KB of K and V)
#pragma unroll
    for (int i = 0; i < 2; ++i) {
        __builtin_amdgcn_global_load_lds(GL1(Kbh + (size_t)w * 1024 + i * 512 + lane * 8),
                                         LDS3(&lK[0][w * 1024 + i * 512]), 16, 0, 0);
        __builtin_amdgcn_global_load_lds(GL1(Vbh + (size_t)w * 1024 + i * 512 + lane * 8),
                                         LDS3(&lV[0][w * 1024 + i * 512]), 16, 0, 0);
    }

    for (int kt = 0; kt < nsteps; ++kt) {
        __syncthreads();   // drains vmcnt -> buf[kt&1] ready; lgkm -> prev reads done
        if (kt + 1 < nsteps) {
            int nb = (kt + 1) & 1;
#pragma unroll
            for (int i = 0; i < 2; ++i) {
                __builtin_amdgcn_global_load_lds(GL1(Kbh + (size_t)(kt + 1) * 4096 + w * 1024 + i * 512 + lane * 8),
                                                 LDS3(&lK[nb][w * 1024 + i * 512]), 16, 0, 0);
                __builtin_amdgcn_global_load_lds(GL1(Vbh + (size_t)(kt + 1) * 4096 + w * 1024 + i * 512 + lane * 8),
                                                 LDS3(&lV[nb][w * 1024 + i * 512]), 16, 0, 0);
            }
        }
        if (kt < nkt) {
            const unsigned short* lKt = lK[kt & 1];
            const unsigned short* lVt = lV[kt & 1];
            if (kt == nkt - 1) {
                if (qt & 1) attn_tile<4, true>(lKt, lVt, lPw, qf, o, ls, kt, qw, lane);
                else        attn_tile<2, true>(lKt, lVt, lPw, qf, o, ls, kt, qw, lane);
            } else {
                attn_tile<4, false>(lKt, lVt, lPw, qf, o, ls, kt, qw, lane);
            }
        }
    }

    // deferred row-sum reduction (per-lane full sum for q=lr) + packed output
    float inv[2];
#pragma unroll
    for (int mt = 0; mt < 2; ++mt) {
        float s = ls[mt];
        s += __shfl_xor(s, 16);
        s += __shfl_xor(s, 32);
        inv[mt] = 1.0f / s;
    }
#pragma unroll
    for (int mt = 0; mt < 2; ++mt) {
#pragma unroll
        for (int nt = 0; nt < 4; ++nt) {
            union { __bf16 h4[4]; uint2 u; } pk;
#pragma unroll
            for (int r = 0; r < 4; ++r) pk.h4[r] = (__bf16)(o[mt][nt][r] * inv[mt]);
            *(uint2*)&Y[((size_t)b * 1024 + qw + mt * 16 + lr) * 384 + h * 64 + nt * 16 + lg * 4] = pk.u;
        }
    }
}

__global__ __launch_bounds__(256, 3) void k_attn(
    const unsigned short* __restrict__ Qf,
    const unsigned short* __restrict__ Kf,
    const unsigned short* __restrict__ Vf,
    unsigned short* __restrict__ Y)
{
    __shared__ unsigned short lK[2][4096];
    __shared__ unsigned short lV[2][4096];
    __shared__ unsigned short lPf[4][2048];

    const int tid = threadIdx.x;
    const int w = tid >> 6, lane = tid & 63;
    const int bh = blockIdx.x;
    const int g = blockIdx.y;                // 0..3; block runs passes g and 7-g
    const int b = bh / 6, h = bh - b * 6;

    const unsigned short* Kbh = Kf + (size_t)bh * 65536;
    const unsigned short* Vbh = Vf + (size_t)bh * 65536;

    attn_pass(g,     w, lane, b, h, bh, Qf, Kbh, Vbh, Y, lK, lV, lPf[w]);
    attn_pass(7 - g, w, lane, b, h, bh, Qf, Kbh, Vbh, Y, lK, lV, lPf[w]);
}

// ---------------- launcher ----------------

extern "C" void kernel_launch(void* const* d_in, const int* in_sizes, int n_in,
                              void* d_out, int out_size, void* d_ws, size_t ws_size,
                              hipStream_t stream)
{
    const float* x  = (const float*)d_in[0];
    const float* Wa = (const float*)d_in[1];
    const float* Wp = (const float*)d_in[2];
    const float* bp = (const float*)d_in[3];
    float* out = (float*)d_out;

    char* ws = (char*)d_ws;
    unsigned short* xb  = (unsigned short*)(ws);              // 25165824 B; reused as Y after attn
    unsigned short* WaT = (unsigned short*)(ws + 25165824);   // 884736 B
    unsigned short* WpT = (unsigned short*)(ws + 26050560);   // 294912 B
    unsigned short* Qb  = (unsigned short*)(ws + 26345472);   // 25165824 B (fragment-major)
    unsigned short* Kb  = (unsigned short*)(ws + 51511296);   // 25165824 B (fragment-major)
    unsigned short* Vtb = (unsigned short*)(ws + 76677120);   // 25165824 B (fragment-major)

    k_prep<<<14592, 256, 0, stream>>>(x, xb, Wa, WaT, Wp, WpT);
    k_gemm_qkv<<<2304, 256, 0, stream>>>(xb, WaT, Qb, Kb, Vtb);
    k_attn<<<dim3(192, 4), 256, 0, stream>>>(Qb, Kb, Vtb, xb);
    k_gemm_proj<<<768, 256, 0, stream>>>(xb, WpT, bp, out);
}